// Round 1
// baseline (512.575 us; speedup 1.0000x reference)
//
#include <hip/hip_runtime.h>
#include <math.h>

#define NRAYS 32768
#define NPTS  200

constexpr unsigned PRIME1 = 2654435761u;
constexpr unsigned PRIME2 = 805459861u;
constexpr unsigned HMASK  = (1u << 19) - 1u;

__device__ __constant__ float    c_scales[6]  = {15.f, 31.f, 63.f, 127.f, 255.f, 511.f};
__device__ __constant__ unsigned c_strides[6] = {17u, 33u, 65u, 129u, 257u, 513u};
__device__ __constant__ unsigned c_offs[6]    = {0u, 4920u, 40864u, 315496u, 839784u, 1364072u};

// Compute the 8 corner table indices for one level at normalized coord q (in [0,1]^3).
// Also outputs frac weights. l may be runtime or compile-time.
__device__ __forceinline__ void corner_indices(int l, float qx, float qy, float qz,
                                               unsigned idx[8],
                                               float& fx, float& fy, float& fz)
{
    const float scale = c_scales[l];
    float px = qx * scale + 0.5f;
    float py = qy * scale + 0.5f;
    float pz = qz * scale + 0.5f;
    float gx = floorf(px), gy = floorf(py), gz = floorf(pz);
    fx = px - gx; fy = py - gy; fz = pz - gz;
    unsigned ix = (unsigned)gx, iy = (unsigned)gy, iz = (unsigned)gz;
    const unsigned off = c_offs[l];
    if (l < 3) {
        const unsigned S  = c_strides[l];
        const unsigned S2 = S * S;
        const unsigned base = off + ix + iy * S + iz * S2;
        idx[0] = base;          idx[1] = base + 1u;
        idx[2] = base + S;      idx[3] = base + S + 1u;
        idx[4] = base + S2;     idx[5] = base + S2 + 1u;
        idx[6] = base + S2 + S; idx[7] = base + S2 + S + 1u;
    } else {
        const unsigned x0 = ix, x1 = ix + 1u;
        const unsigned hy0 = iy * PRIME1, hy1 = hy0 + PRIME1;
        const unsigned hz0 = iz * PRIME2, hz1 = hz0 + PRIME2;
        idx[0] = off + ((x0 ^ hy0 ^ hz0) & HMASK);
        idx[1] = off + ((x1 ^ hy0 ^ hz0) & HMASK);
        idx[2] = off + ((x0 ^ hy1 ^ hz0) & HMASK);
        idx[3] = off + ((x1 ^ hy1 ^ hz0) & HMASK);
        idx[4] = off + ((x0 ^ hy0 ^ hz1) & HMASK);
        idx[5] = off + ((x1 ^ hy0 ^ hz1) & HMASK);
        idx[6] = off + ((x0 ^ hy1 ^ hz1) & HMASK);
        idx[7] = off + ((x1 ^ hy1 ^ hz1) & HMASK);
    }
}

extern "C" __global__ void __launch_bounds__(256)
fused_nerf(const float4* __restrict__ x4,
           const float*  __restrict__ tl,
           const float4* __restrict__ tr,
           const float*  __restrict__ wl,
           const float*  __restrict__ bl,
           const float*  __restrict__ w1, const float* __restrict__ b1,
           const float*  __restrict__ w2, const float* __restrict__ b2,
           const float*  __restrict__ w3, const float* __restrict__ b3,
           const float*  __restrict__ w4, const float* __restrict__ b4,
           float* __restrict__ o_hits,
           float* __restrict__ o_sig,
           float* __restrict__ o_idx,
           float* __restrict__ o_rgb)
{
    const int ray = blockIdx.x;
    const int tid = threadIdx.x;

    __shared__ float s_val[256];
    __shared__ int   s_hit[256];
    __shared__ float s_h0[28];
    __shared__ float s_hA[64];
    __shared__ float s_hB[64];
    __shared__ int   s_fi;
    __shared__ float s_w[64 * 65];

    // ---- per-ray geometry (computed redundantly in every thread; cheap) ----
    const float4 ang = x4[ray];
    float st1, ct1, sp1, cp1, st2, ct2, sp2, cp2;
    sincosf(ang.x, &st1, &ct1);
    sincosf(ang.y, &sp1, &cp1);
    sincosf(ang.z, &st2, &ct2);
    sincosf(ang.w, &sp2, &cp2);
    const float p1x = st1 * cp1, p1y = st1 * sp1, p1z = ct1;
    const float p2x = st2 * cp2, p2y = st2 * sp2, p2z = ct2;
    const float dx = p2x - p1x, dy = p2y - p1y, dz = p2z - p1z;
    float len = sqrtf(dx * dx + dy * dy + dz * dz);
    len = fminf(fmaxf(len, 1e-6f), 1e6f);

    // ---- phase 1: per-sample label encode + sigmoid ----
    float out = -1.0f;
    int first_hit = 0x7fffffff;
    if (tid < NPTS) {
        const float t  = (float)tid / 199.0f;
        const float qx = ((p1x + dx * t) + 1.0f) * 0.5f;
        const float qy = ((p1y + dy * t) + 1.0f) * 0.5f;
        const float qz = ((p1z + dz * t) + 1.0f) * 0.5f;

        float feat[6];
        #pragma unroll
        for (int l = 0; l < 6; ++l) {
            unsigned idx[8];
            float fx, fy, fz;
            corner_indices(l, qx, qy, qz, idx, fx, fy, fz);
            const float ex = 1.0f - fx, ey = 1.0f - fy, ez = 1.0f - fz;
            float v0 = tl[idx[0]], v1 = tl[idx[1]], v2 = tl[idx[2]], v3 = tl[idx[3]];
            float v4 = tl[idx[4]], v5 = tl[idx[5]], v6 = tl[idx[6]], v7 = tl[idx[7]];
            float acc;
            acc = (ex * ey * ez) * v0;
            acc = fmaf(fx * ey * ez, v1, acc);
            acc = fmaf(ex * fy * ez, v2, acc);
            acc = fmaf(fx * fy * ez, v3, acc);
            acc = fmaf(ex * ey * fz, v4, acc);
            acc = fmaf(fx * ey * fz, v5, acc);
            acc = fmaf(ex * fy * fz, v6, acc);
            acc = fmaf(fx * fy * fz, v7, acc);
            feat[l] = acc;
        }
        float z = bl[0];
        #pragma unroll
        for (int l = 0; l < 6; ++l) z = fmaf(feat[l], wl[l], z);
        out = 1.0f / (1.0f + expf(-z));
        o_sig[(size_t)ray * NPTS + tid] = out;
        if (out > 0.5f) first_hit = tid;
    }

    // ---- phase 2: reductions (max sigmoid, first hit index) ----
    s_val[tid] = out;
    s_hit[tid] = first_hit;
    __syncthreads();
    #pragma unroll
    for (int s = 128; s >= 1; s >>= 1) {
        if (tid < s) {
            s_val[tid] = fmaxf(s_val[tid], s_val[tid + s]);
            s_hit[tid] = min(s_hit[tid], s_hit[tid + s]);
        }
        __syncthreads();
    }
    if (tid == 0) {
        o_hits[ray] = s_val[0];
        int fi = (s_hit[0] == 0x7fffffff) ? 0 : s_hit[0];
        s_fi = fi;
        o_idx[ray] = (float)fi;
    }
    __syncthreads();
    const int fi = s_fi;

    // ---- phase 3: RGB encode at hit point (6 threads, one level each) ----
    if (tid < 3) s_h0[tid] = (tid == 0 ? dx : (tid == 1 ? dy : dz)) / len;
    if (tid < 6) {
        const int l = tid;
        const float t  = (float)fi / 199.0f;
        const float qx = ((p1x + dx * t) + 1.0f) * 0.5f;
        const float qy = ((p1y + dy * t) + 1.0f) * 0.5f;
        const float qz = ((p1z + dz * t) + 1.0f) * 0.5f;
        unsigned idx[8];
        float fx, fy, fz;
        corner_indices(l, qx, qy, qz, idx, fx, fy, fz);
        const float ex = 1.0f - fx, ey = 1.0f - fy, ez = 1.0f - fz;
        const float w[8] = { ex * ey * ez, fx * ey * ez, ex * fy * ez, fx * fy * ez,
                             ex * ey * fz, fx * ey * fz, ex * fy * fz, fx * fy * fz };
        float ax = 0.f, ay = 0.f, az = 0.f, aw = 0.f;
        #pragma unroll
        for (int c = 0; c < 8; ++c) {
            float4 v = tr[idx[c]];
            ax = fmaf(w[c], v.x, ax);
            ay = fmaf(w[c], v.y, ay);
            az = fmaf(w[c], v.z, az);
            aw = fmaf(w[c], v.w, aw);
        }
        s_h0[3 + l * 4 + 0] = ax;
        s_h0[3 + l * 4 + 1] = ay;
        s_h0[3 + l * 4 + 2] = az;
        s_h0[3 + l * 4 + 3] = aw;
    }
    __syncthreads();

    // ---- phase 4: MLP 27 -> 64 -> 64 -> 64 -> 3 ----
    if (tid < 64) {
        float acc = b1[tid];
        #pragma unroll
        for (int k = 0; k < 27; ++k) acc = fmaf(s_h0[k], w1[tid * 27 + k], acc);
        s_hA[tid] = fmaxf(acc, 0.0f);
    }
    for (int i = tid; i < 4096; i += 256) s_w[(i >> 6) * 65 + (i & 63)] = w2[i];
    __syncthreads();

    if (tid < 64) {
        float acc = b2[tid];
        #pragma unroll
        for (int k = 0; k < 64; ++k) acc = fmaf(s_hA[k], s_w[tid * 65 + k], acc);
        s_hB[tid] = fmaxf(acc, 0.0f);
    }
    __syncthreads();
    for (int i = tid; i < 4096; i += 256) s_w[(i >> 6) * 65 + (i & 63)] = w3[i];
    __syncthreads();

    if (tid < 64) {
        float acc = b3[tid];
        #pragma unroll
        for (int k = 0; k < 64; ++k) acc = fmaf(s_hB[k], s_w[tid * 65 + k], acc);
        s_hA[tid] = fmaxf(acc, 0.0f);
    }
    __syncthreads();

    if (tid < 3) {
        float acc = b4[tid];
        #pragma unroll
        for (int k = 0; k < 64; ++k) acc = fmaf(s_hA[k], w4[tid * 64 + k], acc);
        o_rgb[ray * 3 + tid] = acc;
    }
}

extern "C" void kernel_launch(void* const* d_in, const int* in_sizes, int n_in,
                              void* d_out, int out_size, void* d_ws, size_t ws_size,
                              hipStream_t stream) {
    const float* x  = (const float*)d_in[0];
    const float* tl = (const float*)d_in[1];
    const float* tr = (const float*)d_in[2];
    const float* wl = (const float*)d_in[3];
    const float* bl = (const float*)d_in[4];
    const float* w1 = (const float*)d_in[5];
    const float* b1 = (const float*)d_in[6];
    const float* w2 = (const float*)d_in[7];
    const float* b2 = (const float*)d_in[8];
    const float* w3 = (const float*)d_in[9];
    const float* b3 = (const float*)d_in[10];
    const float* w4 = (const float*)d_in[11];
    const float* b4 = (const float*)d_in[12];

    float* o      = (float*)d_out;
    float* o_hits = o;
    float* o_sig  = o + NRAYS;
    float* o_idx  = o_sig + (size_t)NRAYS * NPTS;
    float* o_rgb  = o_idx + NRAYS;

    fused_nerf<<<dim3(NRAYS), dim3(256), 0, stream>>>(
        (const float4*)x, tl, (const float4*)tr, wl, bl,
        w1, b1, w2, b2, w3, b3, w4, b4,
        o_hits, o_sig, o_idx, o_rgb);
}

// Round 2
// 494.341 us; speedup vs baseline: 1.0369x; 1.0369x over previous
//
#include <hip/hip_runtime.h>
#include <hip/hip_fp16.h>
#include <math.h>

#define NRAYS 32768
#define NPTS  200
#define T_ROWS 1888360

constexpr unsigned PRIME1 = 2654435761u;
constexpr unsigned PRIME2 = 805459861u;
constexpr unsigned HMASK  = (1u << 19) - 1u;

static __device__ constexpr float    k_scales[6]  = {15.f, 31.f, 63.f, 127.f, 255.f, 511.f};
static __device__ constexpr unsigned k_strides[6] = {17u, 33u, 65u, 129u, 257u, 513u};
static __device__ constexpr unsigned k_offs[6]    = {0u, 4920u, 40864u, 315496u, 839784u, 1364072u};

// extract half (hi ? bits 16-31 : 0-15) of a packed u32 and widen to float
__device__ __forceinline__ float h2f(unsigned pack, unsigned hi) {
    union { unsigned short us; __half h; } cv;
    cv.us = (unsigned short)(hi ? (pack >> 16) : (pack & 0xffffu));
    return __half2float(cv.h);
}

// fp32 corner indices helper (used only for the tiny RGB encode phase)
__device__ __forceinline__ void corner_indices(int l, float qx, float qy, float qz,
                                               unsigned idx[8],
                                               float& fx, float& fy, float& fz)
{
    const float scale = k_scales[l];
    float px = qx * scale + 0.5f;
    float py = qy * scale + 0.5f;
    float pz = qz * scale + 0.5f;
    float gx = floorf(px), gy = floorf(py), gz = floorf(pz);
    fx = px - gx; fy = py - gy; fz = pz - gz;
    unsigned ix = (unsigned)gx, iy = (unsigned)gy, iz = (unsigned)gz;
    const unsigned off = k_offs[l];
    if (l < 3) {
        const unsigned S  = k_strides[l];
        const unsigned S2 = S * S;
        const unsigned base = off + ix + iy * S + iz * S2;
        idx[0] = base;          idx[1] = base + 1u;
        idx[2] = base + S;      idx[3] = base + S + 1u;
        idx[4] = base + S2;     idx[5] = base + S2 + 1u;
        idx[6] = base + S2 + S; idx[7] = base + S2 + S + 1u;
    } else {
        const unsigned x0 = ix, x1 = ix + 1u;
        const unsigned hy0 = iy * PRIME1, hy1 = hy0 + PRIME1;
        const unsigned hz0 = iz * PRIME2, hz1 = hz0 + PRIME2;
        idx[0] = off + ((x0 ^ hy0 ^ hz0) & HMASK);
        idx[1] = off + ((x1 ^ hy0 ^ hz0) & HMASK);
        idx[2] = off + ((x0 ^ hy1 ^ hz0) & HMASK);
        idx[3] = off + ((x1 ^ hy1 ^ hz0) & HMASK);
        idx[4] = off + ((x0 ^ hy0 ^ hz1) & HMASK);
        idx[5] = off + ((x1 ^ hy0 ^ hz1) & HMASK);
        idx[6] = off + ((x0 ^ hy1 ^ hz1) & HMASK);
        idx[7] = off + ((x1 ^ hy1 ^ hz1) & HMASK);
    }
}

// --- K0: fp32 label table -> fp16 in workspace ---
extern "C" __global__ void __launch_bounds__(256)
k_tbl(const float* __restrict__ in, unsigned short* __restrict__ out) {
    int i = blockIdx.x * 256 + threadIdx.x;
    if (i < T_ROWS) {
        union { __half h; unsigned short u; } cv;
        cv.h = __float2half_rn(in[i]);
        out[i] = cv.u;
    }
}

// --- K1: per-ray geometry (kills 256x-redundant sincosf in the main kernel) ---
extern "C" __global__ void __launch_bounds__(256)
k_prep(const float4* __restrict__ x4, float4* __restrict__ geom) {
    int r = blockIdx.x * 256 + threadIdx.x;
    if (r >= NRAYS) return;
    const float4 ang = x4[r];
    float st1, ct1, sp1, cp1, st2, ct2, sp2, cp2;
    sincosf(ang.x, &st1, &ct1);
    sincosf(ang.y, &sp1, &cp1);
    sincosf(ang.z, &st2, &ct2);
    sincosf(ang.w, &sp2, &cp2);
    const float p1x = st1 * cp1, p1y = st1 * sp1, p1z = ct1;
    const float p2x = st2 * cp2, p2y = st2 * sp2, p2z = ct2;
    const float dx = p2x - p1x, dy = p2y - p1y, dz = p2z - p1z;
    float len = sqrtf(dx * dx + dy * dy + dz * dz);
    len = fminf(fmaxf(len, 1e-6f), 1e6f);
    geom[r * 2 + 0] = make_float4(p1x, p1y, p1z, len);
    geom[r * 2 + 1] = make_float4(dx, dy, dz, 0.0f);
}

// --- K2: fused per-ray pipeline ---
extern "C" __global__ void __launch_bounds__(256)
fused_nerf(const float4* __restrict__ geom,
           const unsigned* __restrict__ tbl32,   // fp16 label table, pair-packed
           const float4*  __restrict__ tr,
           const float*   __restrict__ wl,
           const float*   __restrict__ bl,
           const float*   __restrict__ w1, const float* __restrict__ b1,
           const float*   __restrict__ w2, const float* __restrict__ b2,
           const float*   __restrict__ w3, const float* __restrict__ b3,
           const float*   __restrict__ w4, const float* __restrict__ b4,
           float* __restrict__ o_hits,
           float* __restrict__ o_sig,
           float* __restrict__ o_idx,
           float* __restrict__ o_rgb)
{
    const int ray = blockIdx.x;
    const int tid = threadIdx.x;

    __shared__ float s_val[256];
    __shared__ int   s_hit[256];
    __shared__ float s_h0[28];
    __shared__ float s_hA[64];
    __shared__ float s_hB[64];
    __shared__ int   s_fi;
    __shared__ float s_w[64 * 65];

    const float4 g0 = geom[ray * 2 + 0];
    const float4 g1 = geom[ray * 2 + 1];
    const float p1x = g0.x, p1y = g0.y, p1z = g0.z, len = g0.w;
    const float dx = g1.x, dy = g1.y, dz = g1.z;

    // ---- phase 1: per-sample label encode + sigmoid ----
    float out = -1.0f;
    int first_hit = 0x7fffffff;
    if (tid < NPTS) {
        const float t  = (float)tid / 199.0f;
        const float qx = ((p1x + dx * t) + 1.0f) * 0.5f;
        const float qy = ((p1y + dy * t) + 1.0f) * 0.5f;
        const float qz = ((p1z + dz * t) + 1.0f) * 0.5f;

        float feat[6];
        #pragma unroll
        for (int l = 0; l < 6; ++l) {
            const float scale = k_scales[l];
            float px = qx * scale + 0.5f;
            float py = qy * scale + 0.5f;
            float pz = qz * scale + 0.5f;
            float gx = floorf(px), gy = floorf(py), gz = floorf(pz);
            const float fx = px - gx, fy = py - gy, fz = pz - gz;
            unsigned ix = (unsigned)gx, iy = (unsigned)gy, iz = (unsigned)gz;
            const unsigned off = k_offs[l];

            unsigned ia[4], ib[4];
            if (l < 3) {
                const unsigned S  = k_strides[l];
                const unsigned S2 = S * S;
                const unsigned base = off + ix + iy * S + iz * S2;
                ia[0] = base;          ib[0] = base + 1u;
                ia[1] = base + S;      ib[1] = base + S + 1u;
                ia[2] = base + S2;     ib[2] = base + S2 + 1u;
                ia[3] = base + S2 + S; ib[3] = base + S2 + S + 1u;
            } else {
                const unsigned hy0 = iy * PRIME1, hy1 = hy0 + PRIME1;
                const unsigned hz0 = iz * PRIME2, hz1 = hz0 + PRIME2;
                const unsigned e0 = hy0 ^ hz0, e1 = hy1 ^ hz0;
                const unsigned e2 = hy0 ^ hz1, e3 = hy1 ^ hz1;
                const unsigned x1 = ix + 1u;
                ia[0] = off + ((ix ^ e0) & HMASK); ib[0] = off + ((x1 ^ e0) & HMASK);
                ia[1] = off + ((ix ^ e1) & HMASK); ib[1] = off + ((x1 ^ e1) & HMASK);
                ia[2] = off + ((ix ^ e2) & HMASK); ib[2] = off + ((x1 ^ e2) & HMASK);
                ia[3] = off + ((ix ^ e3) & HMASK); ib[3] = off + ((x1 ^ e3) & HMASK);
            }

            const float wx0 = 1.0f - fx, wx1 = fx;
            const float wy0 = 1.0f - fy, wy1 = fy;
            const float wz0 = 1.0f - fz, wz1 = fz;
            const float wyz[4] = { wy0 * wz0, wy1 * wz0, wy0 * wz1, wy1 * wz1 };

            float acc = 0.0f;
            #pragma unroll
            for (int j = 0; j < 4; ++j) {
                const unsigned a = ia[j], b = ib[j];
                const unsigned pa = tbl32[a >> 1];
                const float v0 = h2f(pa, a & 1u);
                float v1;
                if (b == (a ^ 1u)) {
                    // x-pair lives in the same aligned 2-half word: one load served both
                    v1 = h2f(pa, (a & 1u) ^ 1u);
                } else {
                    const unsigned pb = tbl32[b >> 1];
                    v1 = h2f(pb, b & 1u);
                }
                acc = fmaf(wx0 * wyz[j], v0, acc);
                acc = fmaf(wx1 * wyz[j], v1, acc);
            }
            feat[l] = acc;
        }
        float z = bl[0];
        #pragma unroll
        for (int l = 0; l < 6; ++l) z = fmaf(feat[l], wl[l], z);
        out = 1.0f / (1.0f + expf(-z));
        o_sig[(size_t)ray * NPTS + tid] = out;
        if (out > 0.5f) first_hit = tid;
    }

    // ---- phase 2: reductions (max sigmoid, first hit index) ----
    s_val[tid] = out;
    s_hit[tid] = first_hit;
    __syncthreads();
    #pragma unroll
    for (int s = 128; s >= 1; s >>= 1) {
        if (tid < s) {
            s_val[tid] = fmaxf(s_val[tid], s_val[tid + s]);
            s_hit[tid] = min(s_hit[tid], s_hit[tid + s]);
        }
        __syncthreads();
    }
    if (tid == 0) {
        o_hits[ray] = s_val[0];
        int fi = (s_hit[0] == 0x7fffffff) ? 0 : s_hit[0];
        s_fi = fi;
        o_idx[ray] = (float)fi;
    }
    __syncthreads();
    const int fi = s_fi;

    // ---- phase 3: RGB encode at hit point (6 threads, one level each) ----
    if (tid < 3) s_h0[tid] = (tid == 0 ? dx : (tid == 1 ? dy : dz)) / len;
    if (tid < 6) {
        const int l = tid;
        const float t  = (float)fi / 199.0f;
        const float qx = ((p1x + dx * t) + 1.0f) * 0.5f;
        const float qy = ((p1y + dy * t) + 1.0f) * 0.5f;
        const float qz = ((p1z + dz * t) + 1.0f) * 0.5f;
        unsigned idx[8];
        float fx, fy, fz;
        corner_indices(l, qx, qy, qz, idx, fx, fy, fz);
        const float ex = 1.0f - fx, ey = 1.0f - fy, ez = 1.0f - fz;
        const float w[8] = { ex * ey * ez, fx * ey * ez, ex * fy * ez, fx * fy * ez,
                             ex * ey * fz, fx * ey * fz, ex * fy * fz, fx * fy * fz };
        float ax = 0.f, ay = 0.f, az = 0.f, aw = 0.f;
        #pragma unroll
        for (int c = 0; c < 8; ++c) {
            float4 v = tr[idx[c]];
            ax = fmaf(w[c], v.x, ax);
            ay = fmaf(w[c], v.y, ay);
            az = fmaf(w[c], v.z, az);
            aw = fmaf(w[c], v.w, aw);
        }
        s_h0[3 + l * 4 + 0] = ax;
        s_h0[3 + l * 4 + 1] = ay;
        s_h0[3 + l * 4 + 2] = az;
        s_h0[3 + l * 4 + 3] = aw;
    }
    __syncthreads();

    // ---- phase 4: MLP 27 -> 64 -> 64 -> 64 -> 3 ----
    if (tid < 64) {
        float acc = b1[tid];
        #pragma unroll
        for (int k = 0; k < 27; ++k) acc = fmaf(s_h0[k], w1[tid * 27 + k], acc);
        s_hA[tid] = fmaxf(acc, 0.0f);
    }
    for (int i = tid; i < 4096; i += 256) s_w[(i >> 6) * 65 + (i & 63)] = w2[i];
    __syncthreads();

    if (tid < 64) {
        float acc = b2[tid];
        #pragma unroll
        for (int k = 0; k < 64; ++k) acc = fmaf(s_hA[k], s_w[tid * 65 + k], acc);
        s_hB[tid] = fmaxf(acc, 0.0f);
    }
    __syncthreads();
    for (int i = tid; i < 4096; i += 256) s_w[(i >> 6) * 65 + (i & 63)] = w3[i];
    __syncthreads();

    if (tid < 64) {
        float acc = b3[tid];
        #pragma unroll
        for (int k = 0; k < 64; ++k) acc = fmaf(s_hB[k], s_w[tid * 65 + k], acc);
        s_hA[tid] = fmaxf(acc, 0.0f);
    }
    __syncthreads();

    if (tid < 3) {
        float acc = b4[tid];
        #pragma unroll
        for (int k = 0; k < 64; ++k) acc = fmaf(s_hA[k], w4[tid * 64 + k], acc);
        o_rgb[ray * 3 + tid] = acc;
    }
}

extern "C" void kernel_launch(void* const* d_in, const int* in_sizes, int n_in,
                              void* d_out, int out_size, void* d_ws, size_t ws_size,
                              hipStream_t stream) {
    const float* x  = (const float*)d_in[0];
    const float* tl = (const float*)d_in[1];
    const float* tr = (const float*)d_in[2];
    const float* wl = (const float*)d_in[3];
    const float* bl = (const float*)d_in[4];
    const float* w1 = (const float*)d_in[5];
    const float* b1 = (const float*)d_in[6];
    const float* w2 = (const float*)d_in[7];
    const float* b2 = (const float*)d_in[8];
    const float* w3 = (const float*)d_in[9];
    const float* b3 = (const float*)d_in[10];
    const float* w4 = (const float*)d_in[11];
    const float* b4 = (const float*)d_in[12];

    float* o      = (float*)d_out;
    float* o_hits = o;
    float* o_sig  = o + NRAYS;
    float* o_idx  = o_sig + (size_t)NRAYS * NPTS;
    float* o_rgb  = o_idx + NRAYS;

    // workspace layout: [ fp16 table : 3,776,720 B (pad to 3,776,768) | geom : 1 MB ]
    unsigned short* tbl16 = (unsigned short*)d_ws;
    float4*         geom  = (float4*)((char*)d_ws + 3776768);

    k_tbl<<<dim3((T_ROWS + 255) / 256), dim3(256), 0, stream>>>(tl, tbl16);
    k_prep<<<dim3(NRAYS / 256), dim3(256), 0, stream>>>((const float4*)x, geom);
    fused_nerf<<<dim3(NRAYS), dim3(256), 0, stream>>>(
        geom, (const unsigned*)tbl16, (const float4*)tr, wl, bl,
        w1, b1, w2, b2, w3, b3, w4, b4,
        o_hits, o_sig, o_idx, o_rgb);
}

// Round 3
// 372.688 us; speedup vs baseline: 1.3753x; 1.3264x over previous
//
#include <hip/hip_runtime.h>
#include <hip/hip_fp16.h>
#include <math.h>

#define NRAYS 32768
#define NPTS  200
#define RPB   16                 // rays per block
#define PPB   (RPB * NPTS)       // 3200 points per block
#define T_ROWS 1888360
#define DENSE_U32 315496         // u32 words in dense pair region
#define W_U32  1101928           // total u32 words in rebuilt table

constexpr unsigned PRIME1 = 2654435761u;
constexpr unsigned PRIME2 = 805459861u;
constexpr unsigned HMASK  = (1u << 19) - 1u;

static __device__ constexpr float    k_scales[6]  = {15.f, 31.f, 63.f, 127.f, 255.f, 511.f};
static __device__ constexpr unsigned k_strides[6] = {17u, 33u, 65u, 129u, 257u, 513u};
static __device__ constexpr unsigned k_offs[6]    = {0u, 4920u, 40864u, 315496u, 839784u, 1364072u};
// u16-view base of hashed level l (l>=3): 630992 + (l-3)*524288
static __device__ constexpr unsigned k_h16[3] = {630992u, 1155280u, 1679568u};

__device__ __forceinline__ float2 up2(unsigned w) {
    __half2 h = *reinterpret_cast<__half2*>(&w);
    return __half22float2(h);
}

// --- K0: rebuild table: dense levels as (T[i],T[i+1]) fp16 pairs; hashed levels as packed fp16 ---
extern "C" __global__ void __launch_bounds__(256)
k_build(const float* __restrict__ T, unsigned* __restrict__ W) {
    int i = blockIdx.x * 256 + threadIdx.x;
    if (i >= W_U32) return;
    float a, b;
    if (i < DENSE_U32) { a = T[i]; b = T[i + 1]; }
    else { int r = 2 * i - DENSE_U32; a = T[r]; b = T[r + 1]; }
    union { __half h; unsigned short u; } ca, cb;
    ca.h = __float2half_rn(a);
    cb.h = __float2half_rn(b);
    W[i] = (unsigned)ca.u | ((unsigned)cb.u << 16);
}

// fp32 corner indices (RGB encode phase only — reads original fp32 table)
__device__ __forceinline__ void corner_indices(int l, float qx, float qy, float qz,
                                               unsigned idx[8],
                                               float& fx, float& fy, float& fz)
{
    const float scale = k_scales[l];
    float px = qx * scale + 0.5f;
    float py = qy * scale + 0.5f;
    float pz = qz * scale + 0.5f;
    float gx = floorf(px), gy = floorf(py), gz = floorf(pz);
    fx = px - gx; fy = py - gy; fz = pz - gz;
    unsigned ix = (unsigned)gx, iy = (unsigned)gy, iz = (unsigned)gz;
    const unsigned off = k_offs[l];
    if (l < 3) {
        const unsigned S  = k_strides[l];
        const unsigned S2 = S * S;
        const unsigned base = off + ix + iy * S + iz * S2;
        idx[0] = base;          idx[1] = base + 1u;
        idx[2] = base + S;      idx[3] = base + S + 1u;
        idx[4] = base + S2;     idx[5] = base + S2 + 1u;
        idx[6] = base + S2 + S; idx[7] = base + S2 + S + 1u;
    } else {
        const unsigned x0 = ix, x1 = ix + 1u;
        const unsigned hy0 = iy * PRIME1, hy1 = hy0 + PRIME1;
        const unsigned hz0 = iz * PRIME2, hz1 = hz0 + PRIME2;
        idx[0] = off + ((x0 ^ hy0 ^ hz0) & HMASK);
        idx[1] = off + ((x1 ^ hy0 ^ hz0) & HMASK);
        idx[2] = off + ((x0 ^ hy1 ^ hz0) & HMASK);
        idx[3] = off + ((x1 ^ hy1 ^ hz0) & HMASK);
        idx[4] = off + ((x0 ^ hy0 ^ hz1) & HMASK);
        idx[5] = off + ((x1 ^ hy0 ^ hz1) & HMASK);
        idx[6] = off + ((x0 ^ hy1 ^ hz1) & HMASK);
        idx[7] = off + ((x1 ^ hy1 ^ hz1) & HMASK);
    }
}

extern "C" __global__ void __launch_bounds__(256, 4)
fused_nerf(const float4* __restrict__ x4,
           const unsigned* __restrict__ W,     // rebuilt fp16 label table
           const float4*  __restrict__ tr,
           const float*   __restrict__ wl,
           const float*   __restrict__ bl,
           const float*   __restrict__ w1, const float* __restrict__ b1,
           const float*   __restrict__ w2, const float* __restrict__ b2,
           const float*   __restrict__ w3, const float* __restrict__ b3,
           const float*   __restrict__ w4, const float* __restrict__ b4,
           float* __restrict__ o_hits,
           float* __restrict__ o_sig,
           float* __restrict__ o_idx,
           float* __restrict__ o_rgb)
{
    const int tid = threadIdx.x;
    const int ray0 = blockIdx.x * RPB;

    __shared__ float s_w[64 * 64];     // transposed weight stage (w1T/w2T/w3T)
    __shared__ float s_sig[PPB];
    __shared__ float s_geom[RPB * 8];  // p1x,p1y,p1z,len,dx,dy,dz,pad
    __shared__ float s_h0[RPB * 28];   // MLP input per ray
    __shared__ float s_hA[RPB * 64];
    __shared__ float s_hB[RPB * 64];
    __shared__ int   s_fi[RPB];

    // ---- phase 0: per-ray geometry (16 threads, one ray each) ----
    if (tid < RPB) {
        const float4 ang = x4[ray0 + tid];
        float st1, ct1, sp1, cp1, st2, ct2, sp2, cp2;
        sincosf(ang.x, &st1, &ct1);
        sincosf(ang.y, &sp1, &cp1);
        sincosf(ang.z, &st2, &ct2);
        sincosf(ang.w, &sp2, &cp2);
        const float p1x = st1 * cp1, p1y = st1 * sp1, p1z = ct1;
        const float p2x = st2 * cp2, p2y = st2 * sp2, p2z = ct2;
        const float dx = p2x - p1x, dy = p2y - p1y, dz = p2z - p1z;
        float len = sqrtf(dx * dx + dy * dy + dz * dz);
        len = fminf(fmaxf(len, 1e-6f), 1e6f);
        float* g = &s_geom[tid * 8];
        g[0] = p1x; g[1] = p1y; g[2] = p1z; g[3] = len;
        g[4] = dx;  g[5] = dy;  g[6] = dz;  g[7] = 0.f;
    }
    __syncthreads();

    // ---- phase 1: label encode + sigmoid for 3200 points ----
    const size_t sig_base = (size_t)blockIdx.x * PPB;
    auto process = [&](int p) {
        const int r = (p * 5243) >> 20;      // p / 200 for p < 3200
        const int t = p - r * 200;
        const float* g = &s_geom[r * 8];
        const float tt = (float)t / 199.0f;
        const float qx = ((g[0] + g[4] * tt) + 1.0f) * 0.5f;
        const float qy = ((g[1] + g[5] * tt) + 1.0f) * 0.5f;
        const float qz = ((g[2] + g[6] * tt) + 1.0f) * 0.5f;

        float feat[6];
        #pragma unroll
        for (int l = 0; l < 6; ++l) {
            const float scale = k_scales[l];
            float px = qx * scale + 0.5f;
            float py = qy * scale + 0.5f;
            float pz = qz * scale + 0.5f;
            float gx = floorf(px), gy = floorf(py), gz = floorf(pz);
            const float fx = px - gx, fy = py - gy, fz = pz - gz;
            const unsigned ix = (unsigned)gx, iy = (unsigned)gy, iz = (unsigned)gz;
            const float wx0 = 1.0f - fx, wx1 = fx;
            const float wyz[4] = { (1.0f - fy) * (1.0f - fz), fy * (1.0f - fz),
                                   (1.0f - fy) * fz,          fy * fz };
            float acc = 0.0f;
            if (l < 3) {
                const unsigned S  = k_strides[l];
                const unsigned S2 = S * S;
                const unsigned base = k_offs[l] + ix + iy * S + iz * S2;
                const float2 c0 = up2(W[base]);
                const float2 c1 = up2(W[base + S]);
                const float2 c2 = up2(W[base + S2]);
                const float2 c3 = up2(W[base + S2 + S]);
                acc = fmaf(wx0 * wyz[0], c0.x, acc);
                acc = fmaf(wx1 * wyz[0], c0.y, acc);
                acc = fmaf(wx0 * wyz[1], c1.x, acc);
                acc = fmaf(wx1 * wyz[1], c1.y, acc);
                acc = fmaf(wx0 * wyz[2], c2.x, acc);
                acc = fmaf(wx1 * wyz[2], c2.y, acc);
                acc = fmaf(wx0 * wyz[3], c3.x, acc);
                acc = fmaf(wx1 * wyz[3], c3.y, acc);
            } else {
                const unsigned h16 = k_h16[l - 3];
                const unsigned hy0 = iy * PRIME1, hy1 = hy0 + PRIME1;
                const unsigned hz0 = iz * PRIME2, hz1 = hz0 + PRIME2;
                const unsigned x1 = ix + 1u;
                unsigned e[4] = { hy0 ^ hz0, hy1 ^ hz0, hy0 ^ hz1, hy1 ^ hz1 };
                #pragma unroll
                for (int j = 0; j < 4; ++j) {
                    const unsigned a = h16 + ((ix ^ e[j]) & HMASK);
                    const unsigned b = h16 + ((x1 ^ e[j]) & HMASK);
                    const unsigned wa = a >> 1, wb = b >> 1;
                    const float2 fa = up2(W[wa]);
                    const float v0 = (a & 1u) ? fa.y : fa.x;
                    float v1;
                    if (wb == wa) {
                        v1 = (b & 1u) ? fa.y : fa.x;
                    } else {
                        const float2 fb = up2(W[wb]);
                        v1 = (b & 1u) ? fb.y : fb.x;
                    }
                    acc = fmaf(wx0 * wyz[j], v0, acc);
                    acc = fmaf(wx1 * wyz[j], v1, acc);
                }
            }
            feat[l] = acc;
        }
        float z = bl[0];
        #pragma unroll
        for (int l = 0; l < 6; ++l) z = fmaf(feat[l], wl[l], z);
        const float out = 1.0f / (1.0f + __expf(-z));
        o_sig[sig_base + p] = out;
        s_sig[p] = out;
    };

    #pragma unroll 1
    for (int k = 0; k < 6; ++k) {
        const int p0 = tid + k * 512;
        process(p0);          // two independent points -> 2x loads in flight
        process(p0 + 256);
    }
    if (tid < 128) process(tid + 3072);
    __syncthreads();

    // ---- phase 2: per-ray max + first-hit (16 threads per ray) ----
    {
        const int g = tid >> 4, l = tid & 15;
        float vmax = -1.0f;
        int fh = 0x7fff;
        #pragma unroll
        for (int j = 0; j < 13; ++j) {
            const int t = l + j * 16;
            if (t < 200) {
                const float v = s_sig[g * 200 + t];
                vmax = fmaxf(vmax, v);
                if (v > 0.5f) fh = min(fh, t);
            }
        }
        #pragma unroll
        for (int m = 8; m >= 1; m >>= 1) {
            vmax = fmaxf(vmax, __shfl_xor(vmax, m, 64));
            fh = min(fh, __shfl_xor(fh, m, 64));
        }
        if (l == 0) {
            o_hits[ray0 + g] = vmax;
            const int fi = (fh == 0x7fff) ? 0 : fh;
            s_fi[g] = fi;
            o_idx[ray0 + g] = (float)fi;
        }
    }
    __syncthreads();

    // ---- phase 3: dirs + RGB encode at hit points; stage w1T ----
    if (tid < RPB) {
        const float* g = &s_geom[tid * 8];
        const float inv = 1.0f / g[3];
        s_h0[tid * 28 + 0] = g[4] * inv;
        s_h0[tid * 28 + 1] = g[5] * inv;
        s_h0[tid * 28 + 2] = g[6] * inv;
        s_h0[tid * 28 + 27] = 0.f;
    }
    if (tid < RPB * 6) {
        const int r = (tid * 171) >> 10;   // tid / 6
        const int l = tid - r * 6;
        const float* g = &s_geom[r * 8];
        const float t  = (float)s_fi[r] / 199.0f;
        const float qx = ((g[0] + g[4] * t) + 1.0f) * 0.5f;
        const float qy = ((g[1] + g[5] * t) + 1.0f) * 0.5f;
        const float qz = ((g[2] + g[6] * t) + 1.0f) * 0.5f;
        unsigned idx[8];
        float fx, fy, fz;
        corner_indices(l, qx, qy, qz, idx, fx, fy, fz);
        const float ex = 1.0f - fx, ey = 1.0f - fy, ez = 1.0f - fz;
        const float w[8] = { ex * ey * ez, fx * ey * ez, ex * fy * ez, fx * fy * ez,
                             ex * ey * fz, fx * ey * fz, ex * fy * fz, fx * fy * fz };
        float ax = 0.f, ay = 0.f, az = 0.f, aw = 0.f;
        #pragma unroll
        for (int c = 0; c < 8; ++c) {
            float4 v = tr[idx[c]];
            ax = fmaf(w[c], v.x, ax);
            ay = fmaf(w[c], v.y, ay);
            az = fmaf(w[c], v.z, az);
            aw = fmaf(w[c], v.w, aw);
        }
        float* h = &s_h0[r * 28 + 3 + l * 4];
        h[0] = ax; h[1] = ay; h[2] = az; h[3] = aw;
    }
    for (int i = tid; i < 27 * 64; i += 256) {   // w1T: s_w[k*64+n] = w1[n*27+k]
        const int k = i >> 6, n = i & 63;
        s_w[i] = w1[n * 27 + k];
    }
    __syncthreads();

    // ---- phase 4: MLP (16 rays x 64 neurons = 1024 outs, 4 per thread) ----
    const int n = tid & 63;
    const int wv = tid >> 6;
    #pragma unroll
    for (int j = 0; j < 4; ++j) {
        const int r = wv + 4 * j;
        float acc = b1[n];
        #pragma unroll
        for (int k = 0; k < 27; ++k) acc = fmaf(s_h0[r * 28 + k], s_w[k * 64 + n], acc);
        s_hA[r * 64 + n] = fmaxf(acc, 0.0f);
    }
    __syncthreads();
    for (int i = tid; i < 4096; i += 256) s_w[i] = w2[(i & 63) * 64 + (i >> 6)];  // w2T
    __syncthreads();
    #pragma unroll
    for (int j = 0; j < 4; ++j) {
        const int r = wv + 4 * j;
        float acc = b2[n];
        #pragma unroll
        for (int k = 0; k < 64; ++k) acc = fmaf(s_hA[r * 64 + k], s_w[k * 64 + n], acc);
        s_hB[r * 64 + n] = fmaxf(acc, 0.0f);
    }
    __syncthreads();
    for (int i = tid; i < 4096; i += 256) s_w[i] = w3[(i & 63) * 64 + (i >> 6)];  // w3T
    __syncthreads();
    #pragma unroll
    for (int j = 0; j < 4; ++j) {
        const int r = wv + 4 * j;
        float acc = b3[n];
        #pragma unroll
        for (int k = 0; k < 64; ++k) acc = fmaf(s_hB[r * 64 + k], s_w[k * 64 + n], acc);
        s_hA[r * 64 + n] = fmaxf(acc, 0.0f);
    }
    __syncthreads();
    if (tid < RPB * 3) {
        const int r = (tid * 86) >> 8;     // tid / 3
        const int c = tid - r * 3;
        float acc = b4[c];
        #pragma unroll
        for (int k = 0; k < 64; ++k) acc = fmaf(s_hA[r * 64 + k], w4[c * 64 + k], acc);
        o_rgb[(ray0 + r) * 3 + c] = acc;
    }
}

extern "C" void kernel_launch(void* const* d_in, const int* in_sizes, int n_in,
                              void* d_out, int out_size, void* d_ws, size_t ws_size,
                              hipStream_t stream) {
    const float* x  = (const float*)d_in[0];
    const float* tl = (const float*)d_in[1];
    const float* tr = (const float*)d_in[2];
    const float* wl = (const float*)d_in[3];
    const float* bl = (const float*)d_in[4];
    const float* w1 = (const float*)d_in[5];
    const float* b1 = (const float*)d_in[6];
    const float* w2 = (const float*)d_in[7];
    const float* b2 = (const float*)d_in[8];
    const float* w3 = (const float*)d_in[9];
    const float* b3 = (const float*)d_in[10];
    const float* w4 = (const float*)d_in[11];
    const float* b4 = (const float*)d_in[12];

    float* o      = (float*)d_out;
    float* o_hits = o;
    float* o_sig  = o + NRAYS;
    float* o_idx  = o_sig + (size_t)NRAYS * NPTS;
    float* o_rgb  = o_idx + NRAYS;

    unsigned* W = (unsigned*)d_ws;   // 4,407,712 bytes

    k_build<<<dim3((W_U32 + 255) / 256), dim3(256), 0, stream>>>(tl, W);
    fused_nerf<<<dim3(NRAYS / RPB), dim3(256), 0, stream>>>(
        (const float4*)x, W, (const float4*)tr, wl, bl,
        w1, b1, w2, b2, w3, b3, w4, b4,
        o_hits, o_sig, o_idx, o_rgb);
}